// Round 4
// baseline (431.633 us; speedup 1.0000x reference)
//
#include <hip/hip_runtime.h>
#include <hip/hip_bf16.h>

#define BN_EPS 1e-5f
#define NBMAX 512      // max scan blocks (N/256)

typedef __hip_bfloat16 bf16;
typedef __attribute__((ext_vector_type(8))) short short8;
typedef __attribute__((ext_vector_type(4))) float f32x4;

__device__ __forceinline__ float b2f(bf16 v) { return __bfloat162float(v); }
__device__ __forceinline__ bf16 f2b(float v) { return __float2bfloat16(v); }
__device__ __forceinline__ float bl(unsigned u) { return __uint_as_float(u << 16); }
__device__ __forceinline__ float bh(unsigned u) { return __uint_as_float(u & 0xffff0000u); }
__device__ __forceinline__ unsigned pack2(float x, float y) {
    union { bf16 b[2]; unsigned u; } p;
    p.b[0] = f2b(x); p.b[1] = f2b(y);
    return p.u;
}
__device__ __forceinline__ float bs2f(short s) {
    return __uint_as_float(((unsigned)(unsigned short)s) << 16);
}
__device__ __forceinline__ short f2bs(float v) {
    bf16 b = f2b(v);
    return *reinterpret_cast<short*>(&b);
}

// ============ fused: cast x -> bf16 (pad row N = 0) + degree count ============
__global__ __launch_bounds__(256) void initcast_deg_k(
    const float* __restrict__ in, bf16* __restrict__ xb, int n4, int total4,
    const int* __restrict__ dst, int* __restrict__ deg, int E)
{
    const int i = blockIdx.x * 256 + threadIdx.x;
    if (i < total4) {
        if (i < n4) {
            float4 v = ((const float4*)in)[i];
            union { ushort4 u; bf16 b[4]; } p;
            p.b[0] = f2b(v.x); p.b[1] = f2b(v.y); p.b[2] = f2b(v.z); p.b[3] = f2b(v.w);
            ((ushort4*)xb)[i] = p.u;
        } else {
            ushort4 z; z.x = 0; z.y = 0; z.z = 0; z.w = 0;
            ((ushort4*)xb)[i] = z;   // zero pad row N
        }
    }
    if (i < E) atomicAdd(&deg[dst[i]], 1);
}

// ============ scan1: per-block exclusive scan of padded degrees ============
__global__ __launch_bounds__(256) void scan1_k(
    const int* __restrict__ deg, int* __restrict__ lpfx,
    int* __restrict__ bsum, int N)
{
    __shared__ int ssc[256];
    const int t = threadIdx.x;
    const int n = blockIdx.x * 256 + t;
    const int d = (n < N) ? deg[n] : 0;
    const int pv = (d + 7) & ~7;     // pad each row to multiple of 8
    ssc[t] = pv;
    __syncthreads();
    for (int off = 1; off < 256; off <<= 1) {
        int a = (t >= off) ? ssc[t - off] : 0;
        __syncthreads();
        ssc[t] += a;
        __syncthreads();
    }
    if (n < N) lpfx[n] = ssc[t] - pv;
    if (t == 255) bsum[blockIdx.x] = ssc[255];
}

// ============ scan2: exclusive scan over block sums (single block) ============
__global__ __launch_bounds__(512) void scan2_k(int* __restrict__ bs, int nb)
{
    __shared__ int s[512];
    const int t = threadIdx.x;
    const int v = (t < nb) ? bs[t] : 0;
    s[t] = v;
    __syncthreads();
    for (int off = 1; off < 512; off <<= 1) {
        int a = (t >= off) ? s[t - off] : 0;
        __syncthreads();
        s[t] += a;
        __syncthreads();
    }
    if (t < nb) bs[t] = s[t] - v;   // exclusive
}

// ============ finalize: global rowptr/rowend + pad-fill adj with N ============
__global__ __launch_bounds__(256) void finalize_k(
    const int* __restrict__ deg, int* __restrict__ rowptr /* lpfx in */,
    int* __restrict__ rowend, int* __restrict__ adj,
    const int* __restrict__ bsum, int N)
{
    const int n = blockIdx.x * 256 + threadIdx.x;
    if (n >= N) return;
    const int base = bsum[n >> 8] + rowptr[n];
    const int d = deg[n];
    const int pv = (d + 7) & ~7;
    rowptr[n] = base;
    rowend[n] = base + pv;
    for (int i = d; i < pv; i++) adj[base + i] = N;   // pad -> zero row
}

// ============ scatter: adj[rowptr[dst] + pos] = src (pos via atomic dec) ======
__global__ __launch_bounds__(256) void scatter_k(
    const int* __restrict__ src, const int* __restrict__ dst,
    const int* __restrict__ rowptr, int* __restrict__ deg,
    int* __restrict__ adj, int E)
{
    const int e = blockIdx.x * 256 + threadIdx.x;
    if (e >= E) return;
    const int d = dst[e];
    const int pos = atomicSub(&deg[d], 1) - 1;
    adj[rowptr[d] + pos] = src[e];
}

// ========== aggregation: z[n] = h[n] + sum_m h[m]; rows 8-padded, branch-free ==
// 16 lanes per node, dwordx2 loads: one gather instr = full 128B row per group,
// 512B per wave64 instr. Batch of 8 gathers in flight; next adj batch prefetched.
__global__ __launch_bounds__(256, 4) void aggregate_k(
    const bf16* __restrict__ h, const int* __restrict__ rowptr,
    const int* __restrict__ rowend, const int* __restrict__ adj,
    bf16* __restrict__ z, int N)
{
    const int lane16 = threadIdx.x & 15;
    const int n = blockIdx.x * 16 + (threadIdx.x >> 4);
    if (n >= N) return;
    const char* hb_ = (const char*)h;   // row stride 128B
    const int b = rowptr[n], e = rowend[n];

    uint2 u = *(const uint2*)(hb_ + ((size_t)n << 7) + (lane16 << 3));
    float s0 = bl(u.x), s1 = bh(u.x), s2 = bl(u.y), s3 = bh(u.y);

    int m[8];
    if (b < e) {
        #pragma unroll
        for (int k = 0; k < 8; k++) m[k] = adj[b + k];
    }
    for (int i = b; i < e; ) {
        uint2 w[8];
        #pragma unroll
        for (int k = 0; k < 8; k++)
            w[k] = *(const uint2*)(hb_ + (((size_t)(unsigned)m[k]) << 7) + (lane16 << 3));
        const int inext = i + 8;
        if (inext < e) {
            #pragma unroll
            for (int k = 0; k < 8; k++) m[k] = adj[inext + k];
        }
        #pragma unroll
        for (int k = 0; k < 8; k++) {
            s0 += bl(w[k].x); s1 += bh(w[k].x);
            s2 += bl(w[k].y); s3 += bh(w[k].y);
        }
        i = inext;
    }
    uint2 o;
    o.x = pack2(s0, s1);
    o.y = pack2(s2, s3);
    *(uint2*)((char*)z + ((size_t)n << 7) + (lane16 << 3)) = o;
}

// ========== elementwise act: h = relu(y*sc+sh); row N zeroed (pad row) ==========
__global__ __launch_bounds__(256) void ewact_k(
    const bf16* __restrict__ y, const float* __restrict__ sc,
    const float* __restrict__ sh, bf16* __restrict__ h, int N)
{
    const int idx = blockIdx.x * 256 + threadIdx.x;   // one thread = 8 elems
    const int total = (N + 1) * 8;
    if (idx >= total) return;
    short8 v;
    if (idx < N * 8) {
        const int f0 = (idx & 7) * 8;
        v = *(const short8*)(y + (size_t)idx * 8);
        #pragma unroll
        for (int j = 0; j < 8; j++)
            v[j] = f2bs(fmaxf(fmaf(bs2f(v[j]), sc[f0 + j], sh[f0 + j]), 0.f));
    } else {
        #pragma unroll
        for (int j = 0; j < 8; j++) v[j] = 0;
    }
    *(short8*)(h + (size_t)idx * 8) = v;
}

// ---------------- MFMA GEMM (bf16 in/out, f32 acc) ----------------
// C[N x 64] = act(A) @ W + bias.  MODE 0: act = id;  MODE 1: act = relu(A*sc+sh).
// 256 thr = 4 waves; 128 rows/block; per-block stats -> pstat (no atomics).
template<int MODE>
__global__ __launch_bounds__(256) void gemm64_k(
    const bf16* __restrict__ A,
    const float* __restrict__ scin, const float* __restrict__ shin,
    const float* __restrict__ W, const float* __restrict__ bias,
    bf16* __restrict__ out, float* __restrict__ pstat, int nrows)
{
    __shared__ bf16 sWt[64][72];     // transposed W (n-major)
    __shared__ bf16 sC[128][68];     // C tile; 136B rows: 8B-aligned, 2-way bank alias
    __shared__ float sSc[64], sSh[64], sB[64];
    __shared__ float sredS[64][17], sredQ[64][17];
    const int tid = threadIdx.x;

    if (tid < 64) {
        sB[tid] = bias[tid];
        if (MODE == 1) { sSc[tid] = scin[tid]; sSh[tid] = shin[tid]; }
    }
    for (int i = tid; i < 4096; i += 256) {
        int k = i >> 6, n = i & 63;
        sWt[n][k] = f2b(W[i]);
    }
    __syncthreads();

    const int wave = tid >> 6, lane = tid & 63;
    const int quad = lane >> 4, l16 = lane & 15;
    const int row0 = blockIdx.x * 128 + wave * 32;

    short8 a[2][2];
    #pragma unroll
    for (int rt = 0; rt < 2; rt++) {
        int r = row0 + rt * 16 + l16;
        int rr = min(r, nrows - 1);
        const bf16* arow = A + (size_t)rr * 64;
        a[rt][0] = *(const short8*)(arow + quad * 8);
        a[rt][1] = *(const short8*)(arow + 32 + quad * 8);
        if (MODE == 1) {
            #pragma unroll
            for (int j = 0; j < 8; j++) {
                int f0 = quad * 8 + j;
                a[rt][0][j] = f2bs(fmaxf(fmaf(bs2f(a[rt][0][j]), sSc[f0], sSh[f0]), 0.f));
                int f1 = 32 + f0;
                a[rt][1][j] = f2bs(fmaxf(fmaf(bs2f(a[rt][1][j]), sSc[f1], sSh[f1]), 0.f));
            }
        }
    }

    float psS[4], psQ[4];
    #pragma unroll
    for (int t = 0; t < 4; t++) { psS[t] = 0.f; psQ[t] = 0.f; }

    #pragma unroll
    for (int t = 0; t < 4; t++) {
        const int n = t * 16 + l16;
        short8 b0 = *(const short8*)&sWt[n][quad * 8];
        short8 b1 = *(const short8*)&sWt[n][32 + quad * 8];
        const float bn_ = sB[n];
        #pragma unroll
        for (int rt = 0; rt < 2; rt++) {
            f32x4 acc = {0.f, 0.f, 0.f, 0.f};
            acc = __builtin_amdgcn_mfma_f32_16x16x32_bf16(a[rt][0], b0, acc, 0, 0, 0);
            acc = __builtin_amdgcn_mfma_f32_16x16x32_bf16(a[rt][1], b1, acc, 0, 0, 0);
            #pragma unroll
            for (int reg = 0; reg < 4; reg++) {
                const int lr = wave * 32 + rt * 16 + quad * 4 + reg;  // local row
                float v = acc[reg] + bn_;
                sC[lr][n] = f2b(v);
                if (row0 + rt * 16 + quad * 4 + reg < nrows) {
                    psS[t] += v;
                    psQ[t] = fmaf(v, v, psQ[t]);
                }
            }
        }
    }

    #pragma unroll
    for (int t = 0; t < 4; t++) {
        sredS[t * 16 + l16][wave * 4 + quad] = psS[t];
        sredQ[t * 16 + l16][wave * 4 + quad] = psQ[t];
    }
    __syncthreads();

    // coalesced C-tile writeout: 2048 ushort4 chunks (128 rows x 16)
    const int gbase = blockIdx.x * 128;
    #pragma unroll
    for (int it = 0; it < 8; it++) {
        int idx = it * 256 + tid;
        int r = idx >> 4, c4 = idx & 15;
        if (gbase + r < nrows) {
            ushort4 v = *(const ushort4*)&sC[r][c4 * 4];
            *(ushort4*)(out + (size_t)(gbase + r) * 64 + c4 * 4) = v;
        }
    }

    if (tid < 128) {
        const int c = tid & 63;
        const float* p = (tid < 64) ? &sredS[c][0] : &sredQ[c][0];
        float s = 0.f;
        #pragma unroll
        for (int i = 0; i < 16; i++) s += p[i];
        pstat[(size_t)blockIdx.x * 128 + (tid < 64 ? c : 64 + c)] = s;
    }
}

// ---------------- reduce per-block stats -> scale/shift ----------------
__global__ __launch_bounds__(256) void bn_reduce_k(
    const float* __restrict__ pstat, int nblk,
    const float* __restrict__ g, const float* __restrict__ be, float invN,
    float* __restrict__ sc, float* __restrict__ sh)
{
    const int f = blockIdx.x;
    const int t = threadIdx.x;
    float S = 0.f, Q = 0.f;
    for (int b = t; b < nblk; b += 256) {
        S += pstat[(size_t)b * 128 + f];
        Q += pstat[(size_t)b * 128 + 64 + f];
    }
    __shared__ float rs[256], rq[256];
    rs[t] = S; rq[t] = Q;
    __syncthreads();
    for (int off = 128; off > 0; off >>= 1) {
        if (t < off) { rs[t] += rs[t + off]; rq[t] += rq[t + off]; }
        __syncthreads();
    }
    if (t == 0) {
        float m = rs[0] * invN;
        float v = rq[0] * invN - m * m;
        float s = g[f] * rsqrtf(v + BN_EPS);
        sc[f] = s;
        sh[f] = be[f] - m * s;
    }
}

// ---------------- pooled readout; h1 pre-materialized, h2 affine on the fly ------
// 16 groups x 16 lanes; uint2 loads (8B/lane), 4 features per lane.
__global__ __launch_bounds__(256) void pool_readout_k(
    const bf16* __restrict__ xb, const bf16* __restrict__ h1,
    const bf16* __restrict__ y1, const int* __restrict__ batch,
    const float* __restrict__ scB, const float* __restrict__ shB,
    const float* __restrict__ w0, const float* __restrict__ b0,
    const float* __restrict__ w1, const float* __restrict__ b1,
    const float* __restrict__ w2, const float* __restrict__ b2,
    float* __restrict__ out, int Nn)
{
    __shared__ float sB2[2][64];
    __shared__ float p[3][16][64];
    __shared__ float q[3][64];
    const int tid = threadIdx.x;
    if (tid < 64) { sB2[0][tid] = scB[tid]; sB2[1][tid] = shB[tid]; }
    __syncthreads();

    const int g = blockIdx.x;
    int lo = 0, hi = Nn;
    while (lo < hi) { int mid = (lo + hi) >> 1; if (batch[mid] < g) lo = mid + 1; else hi = mid; }
    const int start = lo;
    hi = Nn;
    while (lo < hi) { int mid = (lo + hi) >> 1; if (batch[mid] <= g) lo = mid + 1; else hi = mid; }
    const int end = lo;

    const int l16 = tid & 15, grp = tid >> 4;
    const int f0 = l16 * 4;
    const float scB0 = sB2[0][f0],     shB0 = sB2[1][f0];
    const float scB1 = sB2[0][f0 + 1], shB1 = sB2[1][f0 + 1];
    const float scB2_ = sB2[0][f0 + 2], shB2_ = sB2[1][f0 + 2];
    const float scB3 = sB2[0][f0 + 3], shB3 = sB2[1][f0 + 3];

    float a0 = 0.f, a1 = 0.f, a2 = 0.f, a3 = 0.f;
    float h0 = 0.f, h1s = 0.f, h2 = 0.f, h3 = 0.f;
    float c0 = 0.f, c1 = 0.f, c2 = 0.f, c3 = 0.f;
    for (int i = start + grp; i < end; i += 16) {
        const size_t ro = (size_t)i * 16 + l16;
        uint2 ux = ((const uint2*)xb)[ro];
        uint2 u0 = ((const uint2*)h1)[ro];
        uint2 u1 = ((const uint2*)y1)[ro];
        a0 += bl(ux.x); a1 += bh(ux.x); a2 += bl(ux.y); a3 += bh(ux.y);
        h0 += bl(u0.x); h1s += bh(u0.x); h2 += bl(u0.y); h3 += bh(u0.y);
        c0 += fmaxf(fmaf(bl(u1.x), scB0, shB0), 0.f);
        c1 += fmaxf(fmaf(bh(u1.x), scB1, shB1), 0.f);
        c2 += fmaxf(fmaf(bl(u1.y), scB2_, shB2_), 0.f);
        c3 += fmaxf(fmaf(bh(u1.y), scB3, shB3), 0.f);
    }
    p[0][grp][f0] = a0; p[0][grp][f0 + 1] = a1; p[0][grp][f0 + 2] = a2; p[0][grp][f0 + 3] = a3;
    p[1][grp][f0] = h0; p[1][grp][f0 + 1] = h1s; p[1][grp][f0 + 2] = h2; p[1][grp][f0 + 3] = h3;
    p[2][grp][f0] = c0; p[2][grp][f0 + 1] = c1; p[2][grp][f0 + 2] = c2; p[2][grp][f0 + 3] = c3;
    __syncthreads();

    if (tid < 192) {
        const int arr = tid >> 6, f = tid & 63;
        float s = 0.f;
        #pragma unroll
        for (int i = 0; i < 16; i++) s += p[arr][i][f];
        q[arr][f] = s;
    }
    __syncthreads();

    if (tid < 10) {
        const int c = tid;
        float acc = b0[c] + b1[c] + b2[c];
        for (int k = 0; k < 64; k++) {
            acc = fmaf(q[0][k], w0[k * 10 + c], acc);
            acc = fmaf(q[1][k], w1[k * 10 + c], acc);
            acc = fmaf(q[2][k], w2[k * 10 + c], acc);
        }
        out[(size_t)g * 10 + c] = acc;
    }
}

extern "C" void kernel_launch(void* const* d_in, const int* in_sizes, int n_in,
                              void* d_out, int out_size, void* d_ws, size_t ws_size,
                              hipStream_t stream)
{
    const float* x     = (const float*)d_in[0];
    const int*   edge  = (const int*)d_in[1];
    const int*   batch = (const int*)d_in[2];
    const int N = in_sizes[0] / 64;
    const int E = in_sizes[1] / 2;
    const int G = out_size / 10;
    const int* src = edge;
    const int* dst = edge + E;
    const int NB = (N + 255) / 256;

    const float* c_w1[2]  = {(const float*)d_in[3],  (const float*)d_in[11]};
    const float* c_b1[2]  = {(const float*)d_in[4],  (const float*)d_in[12]};
    const float* c_g1[2]  = {(const float*)d_in[5],  (const float*)d_in[13]};
    const float* c_be1[2] = {(const float*)d_in[6],  (const float*)d_in[14]};
    const float* c_w2[2]  = {(const float*)d_in[7],  (const float*)d_in[15]};
    const float* c_b2[2]  = {(const float*)d_in[8],  (const float*)d_in[16]};
    const float* bn_g[2]  = {(const float*)d_in[9],  (const float*)d_in[17]};
    const float* bn_b[2]  = {(const float*)d_in[10], (const float*)d_in[18]};
    const float* lw[3]    = {(const float*)d_in[19], (const float*)d_in[21], (const float*)d_in[23]};
    const float* lb[3]    = {(const float*)d_in[20], (const float*)d_in[22], (const float*)d_in[24]};

    float* out = (float*)d_out;
    const size_t nh1 = (size_t)(N + 1) * 64;   // node buffers have +1 zero pad row
    const int PG = (N + 127) / 128;   // gemm grid

    // workspace layout
    bf16*  zb    = (bf16*)d_ws;                // nh1 (L0 t/y buffer)
    bf16*  wb    = zb + nh1;                   // nh1 (L1 t/y buffer)
    bf16*  xb    = wb + nh1;                   // nh1 (x cast, row N = 0)
    bf16*  hb    = xb + nh1;                   // nh1 (h1 = act(y0), row N = 0)
    float* scsh  = (float*)(hb + nh1);         // 8 x 64
    float* pstat = scsh + 512;                 // PG x 128
    int*   rowptr = (int*)(pstat + (size_t)PG * 128);  // N (lpfx then final)
    int*   rowend = rowptr + N;                // N
    int*   deg    = rowend + N;                // N (degree, then scatter cursor)
    int*   bsum   = deg + N;                   // NBMAX
    int*   adj    = bsum + NBMAX;              // E + 8N (8-padded rows, packed)

    float* sc0 = scsh;       float* sh0 = scsh + 64;
    float* scA = scsh + 128; float* shA = scsh + 192;
    float* sc2 = scsh + 256; float* sh2 = scsh + 320;
    float* scB = scsh + 384; float* shB = scsh + 448;

    const float invN = 1.0f / (float)N;
    const int aggGrid  = (N + 15) / 16;
    const int n4       = N * 16;               // cast region in 4-elem chunks
    const int total4   = (N + 1) * 16;         // + pad row
    const int castGrid = (max(total4, E) + 255) / 256;
    const int edgeGrid = (E + 255) / 256;
    const int actGrid  = ((N + 1) * 8 + 255) / 256;

    // ---- CSR build: flat atomic (deg -> scan -> finalize -> scatter) ----
    hipMemsetAsync(deg, 0, (size_t)N * sizeof(int), stream);
    initcast_deg_k<<<castGrid, 256, 0, stream>>>(x, xb, n4, total4, dst, deg, E);
    scan1_k<<<NB, 256, 0, stream>>>(deg, rowptr, bsum, N);
    scan2_k<<<1, 512, 0, stream>>>(bsum, NB);
    finalize_k<<<NB, 256, 0, stream>>>(deg, rowptr, rowend, adj, bsum, N);
    scatter_k<<<edgeGrid, 256, 0, stream>>>(src, dst, rowptr, deg, adj, E);

    // ---- layer 0 ----
    aggregate_k<<<aggGrid, 256, 0, stream>>>(xb, rowptr, rowend, adj, zb, N);
    gemm64_k<0><<<PG, 256, 0, stream>>>(zb, nullptr, nullptr,
                                        c_w1[0], c_b1[0], zb, pstat, N);
    bn_reduce_k<<<64, 256, 0, stream>>>(pstat, PG, c_g1[0], c_be1[0], invN, sc0, sh0);
    gemm64_k<1><<<PG, 256, 0, stream>>>(zb, sc0, sh0,
                                        c_w2[0], c_b2[0], zb, pstat, N);
    bn_reduce_k<<<64, 256, 0, stream>>>(pstat, PG, bn_g[0], bn_b[0], invN, scA, shA);

    // ---- h1 = relu(affine(y0)) materialized once (pad row zeroed) ----
    ewact_k<<<actGrid, 256, 0, stream>>>(zb, scA, shA, hb, N);

    // ---- layer 1 ----
    aggregate_k<<<aggGrid, 256, 0, stream>>>(hb, rowptr, rowend, adj, wb, N);
    gemm64_k<0><<<PG, 256, 0, stream>>>(wb, nullptr, nullptr,
                                        c_w1[1], c_b1[1], wb, pstat, N);
    bn_reduce_k<<<64, 256, 0, stream>>>(pstat, PG, c_g1[1], c_be1[1], invN, sc2, sh2);
    gemm64_k<1><<<PG, 256, 0, stream>>>(wb, sc2, sh2,
                                        c_w2[1], c_b2[1], wb, pstat, N);
    bn_reduce_k<<<64, 256, 0, stream>>>(pstat, PG, bn_g[1], bn_b[1], invN, scB, shB);

    // ---- pooled readout (h2 affine+relu fused) ----
    pool_readout_k<<<G, 256, 0, stream>>>(xb, hb, wb, batch,
                                          scB, shB,
                                          lw[0], lb[0], lw[1], lb[1], lw[2], lb[2],
                                          out, N);
}